// Round 8
// baseline (149.932 us; speedup 1.0000x reference)
//
#include <hip/hip_runtime.h>
#include <hip/hip_fp16.h>
#include <stdint.h>

// deform_conv2d: N=8, C=256, H=W=64, OC=256, 3x3, stride=1, pad=1 -> OH=OW=64
// im2col-fused MFMA GEMM. M=32768 (n,oh,ow), N=256 oc, K=2304 (kd = k*256+c).
// R14: B via global_load_lds DMA (T3/T4 complete). R13 analysis: per CU-chunk
//   L1 must return 128 KB (64 KB gathers + 64 KB B, duplicated 2x across
//   waves) ~ the measured wall. Now B is DMA'd once (32 KB, 4 instr/wave, no
//   VGPR return) into double-buffered LDS; frags come from ds_read_b128
//   (contiguous 16B/lane = conflict-free). COMPUTE's only vmem wait is a
//   hand-counted s_waitcnt vmcnt(12) (8 gathers + 4 DMA issued this iter;
//   14 on coords iters; 0 at tail) that retires LAST chunk's DMA -- issued
//   a full chunk earlier, so it never stalls. Gathers-first issue order,
//   AMATH-after-COMPUTE, lgkm-only barrier, 128x256 tile, 1 block/CU kept.
//   B reg double-buffers removed (-64 VGPR). LDS 96 KB.

typedef _Float16 half8 __attribute__((ext_vector_type(8)));
typedef float f32x4 __attribute__((ext_vector_type(4)));

__device__ __forceinline__ __half2 h2(uint32_t u) {
  return __builtin_bit_cast(__half2, u);
}
__device__ __forceinline__ uint32_t packh2f(float a, float b) {
  return __builtin_bit_cast(uint32_t, __floats2half2_rn(a, b));
}
__device__ __forceinline__ __half2 duplo(uint32_t u) {
  return __half2half2(__builtin_bit_cast(__half, (unsigned short)(u & 0xffffu)));
}
__device__ __forceinline__ __half2 duphi(uint32_t u) {
  return __half2half2(__builtin_bit_cast(__half, (unsigned short)(u >> 16)));
}

// ---- merged prep: [0,2048) x NCHW fp32 -> NHWC f16
//                   [2048,4352) weights -> wave-contiguous f16 panels
//                   [4352,5504) offsets -> packed coords {4 x f16 w, 4 x u16 pix}
__global__ __launch_bounds__(256) void prep_all_kernel(
    const float* __restrict__ x, const float* __restrict__ w,
    const float* __restrict__ offset,
    unsigned short* __restrict__ xb, unsigned short* __restrict__ w3s,
    unsigned short* __restrict__ coords) {
  __shared__ float tile[64][65];
  int tid = threadIdx.x;
  if (blockIdx.x < 2048) {
    int bn   = blockIdx.x >> 8;
    int rem  = blockIdx.x & 255;
    int y    = rem >> 2;
    int cblk = rem & 3;
    const float* src = x + ((size_t)(bn * 256 + cblk * 64)) * 4096 + y * 64;
#pragma unroll
    for (int i = 0; i < 4; ++i) {
      int u  = i * 256 + tid;
      int cl = u >> 4;
      int xs = (u & 15) * 4;
      float4 v = *(const float4*)(src + cl * 4096 + xs);
      tile[cl][xs] = v.x; tile[cl][xs + 1] = v.y;
      tile[cl][xs + 2] = v.z; tile[cl][xs + 3] = v.w;
    }
    __syncthreads();
    unsigned short* dst = xb + ((size_t)(bn * 64 + y) * 64) * 256 + cblk * 64;
#pragma unroll
    for (int i = 0; i < 8; ++i) {
      int v2  = i * 256 + tid;
      int xc  = v2 >> 5;
      int cl2 = (v2 & 31) * 2;
      *(uint32_t*)(dst + xc * 256 + cl2) = packh2f(tile[cl2][xc], tile[cl2 + 1][xc]);
    }
  } else if (blockIdx.x < 4352) {
    // w3s layout: chunk t (16384 shorts) = [wcol(4)][nn(4)][ks(2)][lane(64)][e(8)]
    int idx = (blockIdx.x - 2048) * 256 + tid;   // < 589824
    int t    = idx >> 14;
    int r2   = idx & 16383;
    int e    = r2 & 7;
    int lane = (r2 >> 3) & 63;
    int ks   = (r2 >> 9) & 1;
    int nn   = (r2 >> 10) & 3;
    int wcol = (r2 >> 12) & 3;
    int oc = wcol * 64 + nn * 16 + (lane & 15);
    int kk = (ks * 4 + (lane >> 4)) * 8 + e;
    int c  = (t & 3) * 64 + kk;
    int k  = t >> 2;
    w3s[idx] = __builtin_bit_cast(unsigned short, __float2half(w[(oc * 256 + c) * 9 + k]));
  } else {
    int idx = (blockIdx.x - 4352) * 256 + tid;   // < 294912
    int ow  = idx & 63;
    int oh  = (idx >> 6) & 63;
    int r   = idx >> 12;          // bn*9 + k
    int k   = r % 9;
    int bn  = r / 9;
    int ky = k / 3 - 1;
    int kx = k % 3 - 1;
    float offy = offset[((bn * 18 + 2 * k    ) * 64 + oh) * 64 + ow];
    float offx = offset[((bn * 18 + 2 * k + 1) * 64 + oh) * 64 + ow];
    float y = (float)(oh + ky) + offy;
    float x2 = (float)(ow + kx) + offx;
    float y0f = floorf(y), x0f = floorf(x2);
    float fy = y - y0f, fx = x2 - x0f;
    int y0 = (int)y0f, x0 = (int)x0f;
    int y1 = y0 + 1, x1 = x0 + 1;
    float vy0 = (y0 >= 0 && y0 <= 63) ? 1.0f : 0.0f;
    float vy1 = (y1 >= 0 && y1 <= 63) ? 1.0f : 0.0f;
    float vx0 = (x0 >= 0 && x0 <= 63) ? 1.0f : 0.0f;
    float vx1 = (x1 >= 0 && x1 <= 63) ? 1.0f : 0.0f;
    float wy0 = (1.0f - fy) * vy0, wy1 = fy * vy1;
    float wx0 = (1.0f - fx) * vx0, wx1 = fx * vx1;
    int y0c = min(max(y0, 0), 63), y1c = min(max(y1, 0), 63);
    int x0c = min(max(x0, 0), 63), x1c = min(max(x1, 0), 63);
    unsigned short ent[8];
    ent[0] = __builtin_bit_cast(unsigned short, __float2half(wy0 * wx0));
    ent[1] = __builtin_bit_cast(unsigned short, __float2half(wy0 * wx1));
    ent[2] = __builtin_bit_cast(unsigned short, __float2half(wy1 * wx0));
    ent[3] = __builtin_bit_cast(unsigned short, __float2half(wy1 * wx1));
    ent[4] = (unsigned short)(y0c * 64 + x0c);
    ent[5] = (unsigned short)(y0c * 64 + x1c);
    ent[6] = (unsigned short)(y1c * 64 + x0c);
    ent[7] = (unsigned short)(y1c * 64 + x1c);
    *(uint4*)(coords + (size_t)idx * 8) = *(const uint4*)ent;
  }
}

// ---- main: 256 blocks x 512 threads; tile 128 rows x 256 oc; wave 64x64 ----
__global__ __launch_bounds__(512, 2) void deform_mfma_kernel(
    const unsigned short* __restrict__ xb,      // NHWC f16
    const unsigned short* __restrict__ coords,  // packed coord entries
    const unsigned short* __restrict__ w3s,     // wave-contiguous panels f16
    float* __restrict__ out) {                  // (8, 256, 64, 64) fp32
  __shared__ __align__(16) unsigned short At[2][128 * 64];
  __shared__ __align__(16) unsigned short Bt[2][16384];

  int bn  = blockIdx.x & 7;      // XCD swizzle
  int ohp = blockIdx.x >> 3;     // 0..31 -> oh rows {2*ohp, 2*ohp+1}
  int tid = threadIdx.x;

  int w    = tid >> 6;            // wave 0..7
  int lane = tid & 63;
  int wrow = w & 1;               // 64-row half
  int wcol = w >> 1;              // 64-oc quarter
  int mrow = lane & 15;
  int quad = lane >> 4;

  int srow = tid >> 3;             // 0..63
  int sg   = tid & 7;

  const char* xbc = (const char*)(xb + (size_t)bn * (64 * 64 * 256));
  const unsigned short* cb0 = coords + ((size_t)((bn * 9) * 64 + ohp * 2) * 64 + srow) * 8;
  const unsigned short* cb1 = cb0 + 512;   // next oh row

  int aw0  = srow * 64 + ((sg ^ (srow & 7)) * 8);   // shorts; unit2 at +4096
  int grp0 = quad ^ (mrow & 7);                     // ks=0 A frag group
  int grp1 = (4 + quad) ^ (mrow & 7);               // ks=1 A frag group
  int a_base = (wrow * 64 + mrow) * 64;             // + m*1024 (shorts)
  int b_off  = wcol * 4096 + lane * 8;              // shorts; + (nn*2+ks)*512
  int d_off  = w * 2048 + lane * 8;                 // shorts; DMA src slice

  f32x4 acc[4][4] = {};

  __half2 w00, w01, w02, w03, w10, w11, w12, w13;
  uint32_t o00, o01, o02, o03, o10, o11, o12, o13;
  uint4 cn0, cn1;
  uint4 ga0, ga1, ga2, ga3, gb0, gb1, gb2, gb3;

#define CBAR()                                                                  \
  {                                                                             \
    asm volatile("s_waitcnt lgkmcnt(0)" ::: "memory");                          \
    __builtin_amdgcn_s_barrier();                                               \
    asm volatile("" ::: "memory");                                              \
  }

#define BDMA(TT, BB)                                                            \
  {                                                                             \
    const unsigned short* src = w3s + (size_t)(TT) * 16384 + d_off;             \
    unsigned short* dst = &Bt[BB][0] + w * 2048;                                \
    _Pragma("unroll")                                                           \
    for (int j = 0; j < 4; ++j) {                                               \
      __builtin_amdgcn_global_load_lds(                                         \
          (const __attribute__((address_space(1))) void*)(src + j * 512),       \
          (__attribute__((address_space(3))) void*)(dst + j * 512),             \
          16, 0, 0);                                                            \
    }                                                                           \
  }

#define TAPSETUP_R(CE0, CE1)                                                    \
  {                                                                             \
    w00 = duplo((CE0).x); w01 = duphi((CE0).x);                                 \
    w02 = duplo((CE0).y); w03 = duphi((CE0).y);                                 \
    o00 = (((CE0).z & 0xffffu) << 9) + sg * 16;                                 \
    o01 = (((CE0).z >> 16) << 9) + sg * 16;                                     \
    o02 = (((CE0).w & 0xffffu) << 9) + sg * 16;                                 \
    o03 = (((CE0).w >> 16) << 9) + sg * 16;                                     \
    w10 = duplo((CE1).x); w11 = duphi((CE1).x);                                 \
    w12 = duplo((CE1).y); w13 = duphi((CE1).y);                                 \
    o10 = (((CE1).z & 0xffffu) << 9) + sg * 16;                                 \
    o11 = (((CE1).z >> 16) << 9) + sg * 16;                                     \
    o12 = (((CE1).w & 0xffffu) << 9) + sg * 16;                                 \
    o13 = (((CE1).w >> 16) << 9) + sg * 16;                                     \
  }

#define AGATHER(TT)                                                             \
  {                                                                             \
    ga0 = *(const uint4*)(xbc + o00 + ((TT) & 3) * 128);                        \
    ga1 = *(const uint4*)(xbc + o01 + ((TT) & 3) * 128);                        \
    ga2 = *(const uint4*)(xbc + o02 + ((TT) & 3) * 128);                        \
    ga3 = *(const uint4*)(xbc + o03 + ((TT) & 3) * 128);                        \
    gb0 = *(const uint4*)(xbc + o10 + ((TT) & 3) * 128);                        \
    gb1 = *(const uint4*)(xbc + o11 + ((TT) & 3) * 128);                        \
    gb2 = *(const uint4*)(xbc + o12 + ((TT) & 3) * 128);                        \
    gb3 = *(const uint4*)(xbc + o13 + ((TT) & 3) * 128);                        \
  }

#define AMATH(ATP)                                                              \
  {                                                                             \
    __half2 r0 = __hmul2(h2(ga0.x), w00);                                       \
    r0 = __hfma2(h2(ga1.x), w01, r0); r0 = __hfma2(h2(ga2.x), w02, r0);         \
    r0 = __hfma2(h2(ga3.x), w03, r0);                                           \
    __half2 r1 = __hmul2(h2(ga0.y), w00);                                       \
    r1 = __hfma2(h2(ga1.y), w01, r1); r1 = __hfma2(h2(ga2.y), w02, r1);         \
    r1 = __hfma2(h2(ga3.y), w03, r1);                                           \
    __half2 r2 = __hmul2(h2(ga0.z), w00);                                       \
    r2 = __hfma2(h2(ga1.z), w01, r2); r2 = __hfma2(h2(ga2.z), w02, r2);         \
    r2 = __hfma2(h2(ga3.z), w03, r2);                                           \
    __half2 r3 = __hmul2(h2(ga0.w), w00);                                       \
    r3 = __hfma2(h2(ga1.w), w01, r3); r3 = __hfma2(h2(ga2.w), w02, r3);         \
    r3 = __hfma2(h2(ga3.w), w03, r3);                                           \
    uint4 pk;                                                                   \
    pk.x = __builtin_bit_cast(uint32_t, r0);                                    \
    pk.y = __builtin_bit_cast(uint32_t, r1);                                    \
    pk.z = __builtin_bit_cast(uint32_t, r2);                                    \
    pk.w = __builtin_bit_cast(uint32_t, r3);                                    \
    *(uint4*)((ATP) + aw0) = pk;                                                \
    __half2 s0 = __hmul2(h2(gb0.x), w10);                                       \
    s0 = __hfma2(h2(gb1.x), w11, s0); s0 = __hfma2(h2(gb2.x), w12, s0);         \
    s0 = __hfma2(h2(gb3.x), w13, s0);                                           \
    __half2 s1 = __hmul2(h2(gb0.y), w10);                                       \
    s1 = __hfma2(h2(gb1.y), w11, s1); s1 = __hfma2(h2(gb2.y), w12, s1);         \
    s1 = __hfma2(h2(gb3.y), w13, s1);                                           \
    __half2 s2 = __hmul2(h2(gb0.z), w10);                                       \
    s2 = __hfma2(h2(gb1.z), w11, s2); s2 = __hfma2(h2(gb2.z), w12, s2);         \
    s2 = __hfma2(h2(gb3.z), w13, s2);                                           \
    __half2 s3 = __hmul2(h2(gb0.w), w10);                                       \
    s3 = __hfma2(h2(gb1.w), w11, s3); s3 = __hfma2(h2(gb2.w), w12, s3);         \
    s3 = __hfma2(h2(gb3.w), w13, s3);                                           \
    uint4 qk;                                                                   \
    qk.x = __builtin_bit_cast(uint32_t, s0);                                    \
    qk.y = __builtin_bit_cast(uint32_t, s1);                                    \
    qk.z = __builtin_bit_cast(uint32_t, s2);                                    \
    qk.w = __builtin_bit_cast(uint32_t, s3);                                    \
    *(uint4*)((ATP) + aw0 + 4096) = qk;                                         \
  }

#define VMW(N)                                                                  \
  {                                                                             \
    asm volatile("s_waitcnt vmcnt(" #N ")" ::: "memory");                       \
    __builtin_amdgcn_sched_barrier(0);                                          \
  }

#define COMPUTE(ATP, BTP, VM)                                                   \
  {                                                                             \
    VMW(VM)                                                                     \
    half8 bfr[2][4];                                                            \
    _Pragma("unroll")                                                           \
    for (int nn = 0; nn < 4; ++nn) {                                            \
      bfr[0][nn] = *(const half8*)((BTP) + b_off + (nn * 2 + 0) * 512);         \
      bfr[1][nn] = *(const half8*)((BTP) + b_off + (nn * 2 + 1) * 512);         \
    }                                                                           \
    __builtin_amdgcn_s_setprio(1);                                              \
    _Pragma("unroll")                                                           \
    for (int m = 0; m < 4; ++m) {                                               \
      half8 af0 = *(const half8*)((ATP) + a_base + m * 1024 + grp0 * 8);        \
      half8 af1 = *(const half8*)((ATP) + a_base + m * 1024 + grp1 * 8);        \
      _Pragma("unroll")                                                         \
      for (int nn = 0; nn < 4; ++nn) {                                          \
        acc[m][nn] = __builtin_amdgcn_mfma_f32_16x16x32_f16(af0, bfr[0][nn], acc[m][nn], 0, 0, 0); \
        acc[m][nn] = __builtin_amdgcn_mfma_f32_16x16x32_f16(af1, bfr[1][nn], acc[m][nn], 0, 0, 0); \
      }                                                                         \
    }                                                                           \
    __builtin_amdgcn_s_setprio(0);                                              \
  }

  // prologue
  {
    uint4 ce0 = *(const uint4*)cb0;
    uint4 ce1 = *(const uint4*)cb1;
    TAPSETUP_R(ce0, ce1)
  }
  AGATHER(0)
  BDMA(0, 0)
  AMATH(&At[0][0])     // waits gathers(0) only; DMA(0) stays in flight
  CBAR()

  for (int tap = 0; tap < 9; ++tap) {
#pragma unroll
    for (int cc = 0; cc < 4; ++cc) {
      const int t = tap * 4 + cc;
      if (t < 35) {
        if (cc == 3) TAPSETUP_R(cn0, cn1)
        AGATHER(t + 1)
        if (cc & 1) { BDMA(t + 1, 0) } else { BDMA(t + 1, 1) }
        if (cc == 2 && tap < 8) {
          cn0 = *(const uint4*)(cb0 + (tap + 1) * 32768);
          cn1 = *(const uint4*)(cb1 + (tap + 1) * 32768);
        }
      }
      if (cc & 1) {
        if (t == 35) { COMPUTE(&At[1][0], &Bt[1][0], 0) }
        else         { COMPUTE(&At[1][0], &Bt[1][0], 12) }
      } else {
        if (cc == 2 && tap < 8) { COMPUTE(&At[0][0], &Bt[0][0], 14) }
        else                    { COMPUTE(&At[0][0], &Bt[0][0], 12) }
      }
      if (t < 35) {
        if (cc & 1) { AMATH(&At[0][0]) } else { AMATH(&At[1][0]) }
      }
      CBAR()
    }
  }

  // epilogue: C/D layout col=lane&15(oc), row=quad*4+reg(ow)
  float* outp = out + (size_t)bn * 256 * 4096 + (size_t)(ohp * 2 + wrow) * 64;
#pragma unroll
  for (int m = 0; m < 4; ++m) {
    int ow0 = m * 16 + quad * 4;
#pragma unroll
    for (int nn = 0; nn < 4; ++nn) {
      int oc = wcol * 64 + nn * 16 + mrow;
      *(f32x4*)(outp + (size_t)oc * 4096 + ow0) = acc[m][nn];
    }
  }
#undef CBAR
#undef BDMA
#undef TAPSETUP_R
#undef AGATHER
#undef AMATH
#undef VMW
#undef COMPUTE
}

extern "C" void kernel_launch(void* const* d_in, const int* in_sizes, int n_in,
                              void* d_out, int out_size, void* d_ws, size_t ws_size,
                              hipStream_t stream) {
  (void)in_sizes; (void)n_in; (void)out_size; (void)ws_size;
  const float* x      = (const float*)d_in[0];
  const float* offset = (const float*)d_in[1];
  const float* weight = (const float*)d_in[2];
  float* out = (float*)d_out;

  unsigned short* xb     = (unsigned short*)d_ws;                        // 16.78 MB
  unsigned short* w3s    = xb + (size_t)8 * 64 * 64 * 256;               // +1.18 MB
  unsigned short* coords = w3s + (size_t)36 * 16384;                     // +4.72 MB

  prep_all_kernel<<<5504, 256, 0, stream>>>(x, weight, offset, xb, w3s, coords);
  deform_mfma_kernel<<<256, 512, 0, stream>>>(xb, coords, w3s, out);
}

// Round 9
// 144.091 us; speedup vs baseline: 1.0405x; 1.0405x over previous
//
#include <hip/hip_runtime.h>
#include <hip/hip_fp16.h>
#include <stdint.h>

// deform_conv2d: N=8, C=256, H=W=64, OC=256, 3x3, stride=1, pad=1 -> OH=OW=64
// im2col-fused MFMA GEMM. M=32768 (n,oh,ow), N=256 oc, K=2304 (kd = k*256+c).
// R15: counted waits x real co-residency. Audit: R9/R13/R14 all ran 256 blocks
//   = 1 block/CU -- the out-of-phase overlap never existed in any counted-
//   barrier version (MfmaUtil 21% x wall == exactly one block's MFMA load).
//   Now: 512 blocks (2/CU) x 512 thr, tile 64x256 (acc[2][4], ~115 VGPR),
//   B via double-buffered global_load_lds (32KB/chunk, no VGPR return),
//   LDS = At 2x8K + Bt 2x32K = exactly 80KB -> 2 blocks/CU.
//   Two cheap barriers/chunk: ENTRY vmcnt(0)+lgkm(0)+barrier retires only the
//   4 chunk-old DMA (~free) and closes R14's cross-wave Bt race; EXIT lgkm-
//   only barrier -- the 4 fresh DMA cross it in flight. Issue order coords->
//   gathers->DMA; AMATH waits vmcnt(4) (gathers only); COMPUTE waits nothing.
//   launch_bounds(512,4) (cap 128). Spill tripwire: WRITE_SIZE must stay 33MB.

typedef _Float16 half8 __attribute__((ext_vector_type(8)));
typedef float f32x4 __attribute__((ext_vector_type(4)));

__device__ __forceinline__ __half2 h2(uint32_t u) {
  return __builtin_bit_cast(__half2, u);
}
__device__ __forceinline__ uint32_t packh2f(float a, float b) {
  return __builtin_bit_cast(uint32_t, __floats2half2_rn(a, b));
}
__device__ __forceinline__ __half2 duplo(uint32_t u) {
  return __half2half2(__builtin_bit_cast(__half, (unsigned short)(u & 0xffffu)));
}
__device__ __forceinline__ __half2 duphi(uint32_t u) {
  return __half2half2(__builtin_bit_cast(__half, (unsigned short)(u >> 16)));
}

// ---- merged prep: [0,2048) x NCHW fp32 -> NHWC f16
//                   [2048,4352) weights -> wave-contiguous f16 panels
//                   [4352,5504) offsets -> packed coords {4 x f16 w, 4 x u16 pix}
__global__ __launch_bounds__(256) void prep_all_kernel(
    const float* __restrict__ x, const float* __restrict__ w,
    const float* __restrict__ offset,
    unsigned short* __restrict__ xb, unsigned short* __restrict__ w3s,
    unsigned short* __restrict__ coords) {
  __shared__ float tile[64][65];
  int tid = threadIdx.x;
  if (blockIdx.x < 2048) {
    int bn   = blockIdx.x >> 8;
    int rem  = blockIdx.x & 255;
    int y    = rem >> 2;
    int cblk = rem & 3;
    const float* src = x + ((size_t)(bn * 256 + cblk * 64)) * 4096 + y * 64;
#pragma unroll
    for (int i = 0; i < 4; ++i) {
      int u  = i * 256 + tid;
      int cl = u >> 4;
      int xs = (u & 15) * 4;
      float4 v = *(const float4*)(src + cl * 4096 + xs);
      tile[cl][xs] = v.x; tile[cl][xs + 1] = v.y;
      tile[cl][xs + 2] = v.z; tile[cl][xs + 3] = v.w;
    }
    __syncthreads();
    unsigned short* dst = xb + ((size_t)(bn * 64 + y) * 64) * 256 + cblk * 64;
#pragma unroll
    for (int i = 0; i < 8; ++i) {
      int v2  = i * 256 + tid;
      int xc  = v2 >> 5;
      int cl2 = (v2 & 31) * 2;
      *(uint32_t*)(dst + xc * 256 + cl2) = packh2f(tile[cl2][xc], tile[cl2 + 1][xc]);
    }
  } else if (blockIdx.x < 4352) {
    // w3s layout: chunk t (16384 shorts) = [wcol(4)][nn(4)][ks(2)][lane(64)][e(8)]
    int idx = (blockIdx.x - 2048) * 256 + tid;   // < 589824
    int t    = idx >> 14;
    int r2   = idx & 16383;
    int e    = r2 & 7;
    int lane = (r2 >> 3) & 63;
    int ks   = (r2 >> 9) & 1;
    int nn   = (r2 >> 10) & 3;
    int wcol = (r2 >> 12) & 3;
    int oc = wcol * 64 + nn * 16 + (lane & 15);
    int kk = (ks * 4 + (lane >> 4)) * 8 + e;
    int c  = (t & 3) * 64 + kk;
    int k  = t >> 2;
    w3s[idx] = __builtin_bit_cast(unsigned short, __float2half(w[(oc * 256 + c) * 9 + k]));
  } else {
    int idx = (blockIdx.x - 4352) * 256 + tid;   // < 294912
    int ow  = idx & 63;
    int oh  = (idx >> 6) & 63;
    int r   = idx >> 12;          // bn*9 + k
    int k   = r % 9;
    int bn  = r / 9;
    int ky = k / 3 - 1;
    int kx = k % 3 - 1;
    float offy = offset[((bn * 18 + 2 * k    ) * 64 + oh) * 64 + ow];
    float offx = offset[((bn * 18 + 2 * k + 1) * 64 + oh) * 64 + ow];
    float y = (float)(oh + ky) + offy;
    float x2 = (float)(ow + kx) + offx;
    float y0f = floorf(y), x0f = floorf(x2);
    float fy = y - y0f, fx = x2 - x0f;
    int y0 = (int)y0f, x0 = (int)x0f;
    int y1 = y0 + 1, x1 = x0 + 1;
    float vy0 = (y0 >= 0 && y0 <= 63) ? 1.0f : 0.0f;
    float vy1 = (y1 >= 0 && y1 <= 63) ? 1.0f : 0.0f;
    float vx0 = (x0 >= 0 && x0 <= 63) ? 1.0f : 0.0f;
    float vx1 = (x1 >= 0 && x1 <= 63) ? 1.0f : 0.0f;
    float wy0 = (1.0f - fy) * vy0, wy1 = fy * vy1;
    float wx0 = (1.0f - fx) * vx0, wx1 = fx * vx1;
    int y0c = min(max(y0, 0), 63), y1c = min(max(y1, 0), 63);
    int x0c = min(max(x0, 0), 63), x1c = min(max(x1, 0), 63);
    unsigned short ent[8];
    ent[0] = __builtin_bit_cast(unsigned short, __float2half(wy0 * wx0));
    ent[1] = __builtin_bit_cast(unsigned short, __float2half(wy0 * wx1));
    ent[2] = __builtin_bit_cast(unsigned short, __float2half(wy1 * wx0));
    ent[3] = __builtin_bit_cast(unsigned short, __float2half(wy1 * wx1));
    ent[4] = (unsigned short)(y0c * 64 + x0c);
    ent[5] = (unsigned short)(y0c * 64 + x1c);
    ent[6] = (unsigned short)(y1c * 64 + x0c);
    ent[7] = (unsigned short)(y1c * 64 + x1c);
    *(uint4*)(coords + (size_t)idx * 8) = *(const uint4*)ent;
  }
}

// ---- main: 512 blocks x 512 threads; tile 64 rows x 256 oc; wave 32x64 ----
__global__ __launch_bounds__(512, 4) void deform_mfma_kernel(
    const unsigned short* __restrict__ xb,      // NHWC f16
    const unsigned short* __restrict__ coords,  // packed coord entries
    const unsigned short* __restrict__ w3s,     // wave-contiguous panels f16
    float* __restrict__ out) {                  // (8, 256, 64, 64) fp32
  // At 2x8KB (XOR group swizzle) + Bt 2x32KB (linear DMA image) = 80KB exactly
  // -> 2 blocks/CU.
  __shared__ __align__(16) unsigned short At[2][64 * 64];
  __shared__ __align__(16) unsigned short Bt[2][16384];

  int bn  = blockIdx.x & 7;      // XCD swizzle
  int oh  = blockIdx.x >> 3;     // 0..63
  int tid = threadIdx.x;

  int w    = tid >> 6;            // wave 0..7
  int lane = tid & 63;
  int wrow = w & 1;               // 32-row half
  int wcol = w >> 1;              // 64-oc quarter
  int mrow = lane & 15;
  int quad = lane >> 4;

  // staging identity: one thread = one (row, 8-ch group) unit
  int srow = tid >> 3;             // 0..63
  int sg   = tid & 7;

  const char* xbc = (const char*)(xb + (size_t)bn * (64 * 64 * 256));
  const unsigned short* cb = coords + ((size_t)((bn * 9) * 64 + oh) * 64 + srow) * 8;

  int aw0  = srow * 64 + ((sg ^ (srow & 7)) * 8);   // XOR-swizzled slot (shorts)
  int grp0 = quad ^ (mrow & 7);                     // ks=0 A frag group
  int grp1 = (4 + quad) ^ (mrow & 7);               // ks=1 A frag group
  int a_base = (wrow * 32 + mrow) * 64;             // + m*1024 (shorts)
  int b_off  = wcol * 4096 + lane * 8;              // shorts; + (nn*2+ks)*512
  int d_off  = w * 2048 + lane * 8;                 // shorts; DMA src slice

  f32x4 acc[2][4] = {};

  __half2 w00, w01, w02, w03;
  uint32_t o00, o01, o02, o03;
  uint4 cn;
  uint4 ga0, ga1, ga2, ga3;       // in-flight corner gathers

  // ENTRY barrier: retire chunk-old DMA (aged ~1 chunk, ~free) + make ALL
  // waves' DMA visible before any Bt read (fixes cross-wave DMA race).
#define EBAR()                                                                  \
  {                                                                             \
    asm volatile("s_waitcnt vmcnt(0) lgkmcnt(0)" ::: "memory");                 \
    __builtin_amdgcn_sched_barrier(0);                                          \
    __builtin_amdgcn_s_barrier();                                               \
    asm volatile("" ::: "memory");                                              \
  }
  // EXIT barrier: LDS-order only; fresh DMA crosses in flight (T4).
#define CBAR()                                                                  \
  {                                                                             \
    asm volatile("s_waitcnt lgkmcnt(0)" ::: "memory");                          \
    __builtin_amdgcn_s_barrier();                                               \
    asm volatile("" ::: "memory");                                              \
  }
#define VMW(N)                                                                  \
  {                                                                             \
    asm volatile("s_waitcnt vmcnt(" #N ")" ::: "memory");                       \
    __builtin_amdgcn_sched_barrier(0);                                          \
  }

  // B chunk -> LDS via DMA: 4 x 1KB per wave, no VGPR return
#define BDMA(TT, BB)                                                            \
  {                                                                             \
    const unsigned short* src = w3s + (size_t)(TT) * 16384 + d_off;             \
    unsigned short* dst = &Bt[BB][0] + w * 2048;                                \
    _Pragma("unroll")                                                           \
    for (int j = 0; j < 4; ++j) {                                               \
      __builtin_amdgcn_global_load_lds(                                         \
          (const __attribute__((address_space(1))) void*)(src + j * 512),       \
          (__attribute__((address_space(3))) void*)(dst + j * 512),             \
          16, 0, 0);                                                            \
    }                                                                           \
  }

#define TAPSETUP_R(CE)                                                          \
  {                                                                             \
    w00 = duplo((CE).x); w01 = duphi((CE).x);                                   \
    w02 = duplo((CE).y); w03 = duphi((CE).y);                                   \
    o00 = (((CE).z & 0xffffu) << 9) + sg * 16;                                  \
    o01 = (((CE).z >> 16) << 9) + sg * 16;                                      \
    o02 = (((CE).w & 0xffffu) << 9) + sg * 16;                                  \
    o03 = (((CE).w >> 16) << 9) + sg * 16;                                      \
  }

  // issue the 4 corner gathers for one unit; before BDMA in program order
#define AGATHER(TT)                                                             \
  {                                                                             \
    ga0 = *(const uint4*)(xbc + o00 + ((TT) & 3) * 128);                        \
    ga1 = *(const uint4*)(xbc + o01 + ((TT) & 3) * 128);                        \
    ga2 = *(const uint4*)(xbc + o02 + ((TT) & 3) * 128);                        \
    ga3 = *(const uint4*)(xbc + o03 + ((TT) & 3) * 128);                        \
  }

  // packed-f16 bilinear combine + LDS write; VMW(4) retires gathers, keeps DMA
#define AMATH(ATP)                                                              \
  {                                                                             \
    VMW(4)                                                                      \
    __half2 r0 = __hmul2(h2(ga0.x), w00);                                       \
    r0 = __hfma2(h2(ga1.x), w01, r0); r0 = __hfma2(h2(ga2.x), w02, r0);         \
    r0 = __hfma2(h2(ga3.x), w03, r0);                                           \
    __half2 r1 = __hmul2(h2(ga0.y), w00);                                       \
    r1 = __hfma2(h2(ga1.y), w01, r1); r1 = __hfma2(h2(ga2.y), w02, r1);         \
    r1 = __hfma2(h2(ga3.y), w03, r1);                                           \
    __half2 r2 = __hmul2(h2(ga0.z), w00);                                       \
    r2 = __hfma2(h2(ga1.z), w01, r2); r2 = __hfma2(h2(ga2.z), w02, r2);         \
    r2 = __hfma2(h2(ga3.z), w03, r2);                                           \
    __half2 r3 = __hmul2(h2(ga0.w), w00);                                       \
    r3 = __hfma2(h2(ga1.w), w01, r3); r3 = __hfma2(h2(ga2.w), w02, r3);         \
    r3 = __hfma2(h2(ga3.w), w03, r3);                                           \
    uint4 pk;                                                                   \
    pk.x = __builtin_bit_cast(uint32_t, r0);                                    \
    pk.y = __builtin_bit_cast(uint32_t, r1);                                    \
    pk.z = __builtin_bit_cast(uint32_t, r2);                                    \
    pk.w = __builtin_bit_cast(uint32_t, r3);                                    \
    *(uint4*)((ATP) + aw0) = pk;                                                \
  }

  // no vmem wait: B(t) guaranteed by ENTRY barrier, A(t) by prev EXIT barrier
#define COMPUTE(ATP, BTP)                                                       \
  {                                                                             \
    half8 bfr[2][4];                                                            \
    _Pragma("unroll")                                                           \
    for (int nn = 0; nn < 4; ++nn) {                                            \
      bfr[0][nn] = *(const half8*)((BTP) + b_off + (nn * 2 + 0) * 512);         \
      bfr[1][nn] = *(const half8*)((BTP) + b_off + (nn * 2 + 1) * 512);         \
    }                                                                           \
    __builtin_amdgcn_s_setprio(1);                                              \
    _Pragma("unroll")                                                           \
    for (int m = 0; m < 2; ++m) {                                               \
      half8 af0 = *(const half8*)((ATP) + a_base + m * 1024 + grp0 * 8);        \
      half8 af1 = *(const half8*)((ATP) + a_base + m * 1024 + grp1 * 8);        \
      _Pragma("unroll")                                                         \
      for (int nn = 0; nn < 4; ++nn) {                                          \
        acc[m][nn] = __builtin_amdgcn_mfma_f32_16x16x32_f16(af0, bfr[0][nn], acc[m][nn], 0, 0, 0); \
        acc[m][nn] = __builtin_amdgcn_mfma_f32_16x16x32_f16(af1, bfr[1][nn], acc[m][nn], 0, 0, 0); \
      }                                                                         \
    }                                                                           \
    __builtin_amdgcn_s_setprio(0);                                              \
  }

  // ---- prologue: coords, gathers(0), DMA(0)->Bt[0], stage A(0) ----
  {
    uint4 ce0 = *(const uint4*)cb;   // vmem #1 (oldest)
    AGATHER(0)                       // needs o00..o03 -> must setup first
    // NOTE: TAPSETUP_R needs ce0 value; compiler inserts the dependency wait.
    TAPSETUP_R(ce0)
  }
  // re-issue gathers after setup (the block above couldn't gather before setup)
  AGATHER(0)
  BDMA(0, 0)
  AMATH(&At[0][0])                   // VMW(4): retires coords+gathers, keeps DMA
  CBAR()

  for (int tap = 0; tap < 9; ++tap) {
#pragma unroll
    for (int cc = 0; cc < 4; ++cc) {
      const int t = tap * 4 + cc;
      // ---- ENTRY: retire DMA(t) (aged), all-wave visibility for Bt[t&1] ----
      EBAR()
      // ---- issue t+1 vmem: coords (oldest), gathers, DMA (newest) ----
      if (t < 35) {
        if (cc == 3) TAPSETUP_R(cn)   // VALU-only; cn retired by prev VMW(4)
        if (cc == 2 && tap < 8) cn = *(const uint4*)(cb + (tap + 1) * 32768);
        AGATHER(t + 1)
        if (cc & 1) { BDMA(t + 1, 0) } else { BDMA(t + 1, 1) }
      }
      // ---- compute chunk t (no vmem wait) ----
      if (cc & 1) { COMPUTE(&At[1][0], &Bt[1][0]) } else { COMPUTE(&At[0][0], &Bt[0][0]) }
      // ---- finish A(t+1) staging: VMW(4) keeps DMA(t+1) in flight ----
      if (t < 35) {
        if (cc & 1) { AMATH(&At[0][0]) } else { AMATH(&At[1][0]) }
      }
      // ---- EXIT: LDS order only; DMA(t+1) crosses in flight ----
      CBAR()
    }
  }

  // ---- epilogue: C/D layout col=lane&15(oc), row=quad*4+reg(ow) ----
  float* outp = out + (size_t)bn * 256 * 4096 + (size_t)oh * 64;
#pragma unroll
  for (int m = 0; m < 2; ++m) {
    int ow0 = wrow * 32 + m * 16 + quad * 4;
#pragma unroll
    for (int nn = 0; nn < 4; ++nn) {
      int oc = wcol * 64 + nn * 16 + mrow;
      *(f32x4*)(outp + (size_t)oc * 4096 + ow0) = acc[m][nn];
    }
  }
#undef EBAR
#undef CBAR
#undef VMW
#undef BDMA
#undef TAPSETUP_R
#undef AGATHER
#undef AMATH
#undef COMPUTE
}

extern "C" void kernel_launch(void* const* d_in, const int* in_sizes, int n_in,
                              void* d_out, int out_size, void* d_ws, size_t ws_size,
                              hipStream_t stream) {
  (void)in_sizes; (void)n_in; (void)out_size; (void)ws_size;
  const float* x      = (const float*)d_in[0];
  const float* offset = (const float*)d_in[1];
  const float* weight = (const float*)d_in[2];
  float* out = (float*)d_out;

  unsigned short* xb     = (unsigned short*)d_ws;                        // 16.78 MB
  unsigned short* w3s    = xb + (size_t)8 * 64 * 64 * 256;               // +1.18 MB
  unsigned short* coords = w3s + (size_t)36 * 16384;                     // +4.72 MB

  prep_all_kernel<<<5504, 256, 0, stream>>>(x, weight, offset, xb, w3s, coords);
  deform_mfma_kernel<<<512, 512, 0, stream>>>(xb, coords, w3s, out);
}